// Round 10
// baseline (169.871 us; speedup 1.0000x reference)
//
#include <hip/hip_runtime.h>
#include <hip/hip_bf16.h>

// ---------------------------------------------------------------------------
// GCN forward: 2x (GCNConv -> BN(eval) -> ReLU) -> mean-pool -> MLP
// N=100000 nodes, E=1e6 edges, feats 64->64->32, 500 graphs, out [500,2] f32
// R1: scatter-atomics -> CSR-by-dst gather; hs pre-scaled by dis[row].
// R2: self-loop term fix.   R3: LDS-tiled register-blocked GEMMs.
// R4: hs1/hs2 stored bf16 -> halves random gather traffic.
// R5: CSR build via bucketed counting sort.
// R6: sub-wave-per-node gathers with 4B/lane packed-bf16 loads.
// R7: k_pool grid 1024.   R8: 8-edge unrolled gathers.
// R9: gemm32 FUSED into gather64 epilogue (W2 + act rows staged in LDS,
//     each lane computes one of 32 outputs) -> act1 buffer deleted,
//     ~51MB traffic and one launch removed.
// ---------------------------------------------------------------------------

#define CHUNK 4096

// zero bucketCnt[512] and sums/cntG (nSums floats)
__global__ void k_zero_misc(int* __restrict__ bucketCnt, float* __restrict__ sums,
                            int nSums) {
    int i = blockIdx.x * blockDim.x + threadIdx.x;
    if (i < 512) bucketCnt[i] = 0;
    int j = i - 512;
    if (j >= 0 && j < nSums) sums[j] = 0.f;
}

// LDS-aggregated histogram of dst>>8 into bucketCnt[512]
__global__ __launch_bounds__(256) void k_hist(const int* __restrict__ dst,
                                              int* __restrict__ bucketCnt, int E) {
    __shared__ int lh[512];
    for (int i = threadIdx.x; i < 512; i += 256) lh[i] = 0;
    __syncthreads();
    int base = blockIdx.x * CHUNK;
    for (int i = threadIdx.x; i < CHUNK; i += 256) {
        int e = base + i;
        if (e < E) atomicAdd(&lh[dst[e] >> 8], 1);
    }
    __syncthreads();
    for (int i = threadIdx.x; i < 512; i += 256)
        if (lh[i]) atomicAdd(&bucketCnt[i], lh[i]);
}

// exclusive scan of bucketCnt -> bucketStart, bucketCursor (one block, 512 thr)
__global__ void k_scan512(const int* __restrict__ bucketCnt,
                          int* __restrict__ bucketStart,
                          int* __restrict__ bucketCursor) {
    __shared__ int s[512];
    int tid = threadIdx.x;
    int v = bucketCnt[tid];
    s[tid] = v;
    __syncthreads();
    for (int off = 1; off < 512; off <<= 1) {
        int t = (tid >= off) ? s[tid - off] : 0;
        __syncthreads();
        s[tid] += t;
        __syncthreads();
    }
    int excl = s[tid] - v;
    bucketStart[tid] = excl;
    bucketCursor[tid] = excl;
    if (tid == 511) bucketStart[512] = s[511];   // = E
}

// scatter packed (src<<8 | dst&255) into bucket regions, block-aggregated
__global__ __launch_bounds__(256) void k_binpairs(
    const int* __restrict__ src, const int* __restrict__ dst,
    int* __restrict__ bucketCursor, unsigned* __restrict__ pairs, int E) {
    __shared__ int lh[512];
    __shared__ int lbase[512];
    for (int i = threadIdx.x; i < 512; i += 256) lh[i] = 0;
    __syncthreads();
    int base = blockIdx.x * CHUNK;
    for (int i = threadIdx.x; i < CHUNK; i += 256) {
        int e = base + i;
        if (e < E) atomicAdd(&lh[dst[e] >> 8], 1);
    }
    __syncthreads();
    for (int i = threadIdx.x; i < 512; i += 256) {
        int c = lh[i];
        lbase[i] = c ? atomicAdd(&bucketCursor[i], c) : 0;
        lh[i] = 0;   // reuse as local cursor
    }
    __syncthreads();
    for (int i = threadIdx.x; i < CHUNK; i += 256) {
        int e = base + i;
        if (e < E) {
            int d = dst[e];
            int b = d >> 8;
            int r = atomicAdd(&lh[b], 1);
            pairs[lbase[b] + r] = ((unsigned)src[e] << 8) | (unsigned)(d & 255);
        }
    }
}

// per-bucket (256 nodes) LDS counting sort -> rowStart, dis, perm
__global__ __launch_bounds__(256) void k_csr(
    const unsigned* __restrict__ pairs, const int* __restrict__ bucketStart,
    int* __restrict__ rowStart, float* __restrict__ dis, int* __restrict__ perm,
    int n, int E) {
    __shared__ int cnt[256];
    __shared__ int s[256];
    __shared__ int cur[256];
    int b = blockIdx.x, tid = threadIdx.x;
    int r0 = bucketStart[b], r1 = bucketStart[b + 1];
    cnt[tid] = 0;
    __syncthreads();
    for (int i = r0 + tid; i < r1; i += 256) atomicAdd(&cnt[pairs[i] & 255], 1);
    __syncthreads();
    int v = cnt[tid];
    s[tid] = v;
    __syncthreads();
    for (int off = 1; off < 256; off <<= 1) {
        int t = (tid >= off) ? s[tid - off] : 0;
        __syncthreads();
        s[tid] += t;
        __syncthreads();
    }
    int excl = s[tid] - v;
    int node = b * 256 + tid;
    if (node < n) {
        rowStart[node] = r0 + excl;
        dis[node] = rsqrtf((float)v + 1.0f);   // in-degree + self-loop
    }
    if (b == 0 && tid == 0) rowStart[n] = E;
    cur[tid] = excl;
    __syncthreads();
    for (int i = r0 + tid; i < r1; i += 256) {
        unsigned p = pairs[i];
        int lo = p & 255;
        int slot = atomicAdd(&cur[lo], 1);
        perm[r0 + slot] = (int)(p >> 8);
    }
}

// hs = bf16((x @ W) * dis[row]). Tile 128x64, thread tile 4 rows x 8 cols.
__global__ __launch_bounds__(256) void k_gemm64(
    const float* __restrict__ x, const float* __restrict__ W,
    const float* __restrict__ dis, __hip_bfloat16* __restrict__ hs, int n) {
    __shared__ float Ws[64 * 64];
    __shared__ float xs[128][65];          // odd stride: conflict-free
    const int tid = threadIdx.x;
    for (int i = tid * 4; i < 4096; i += 1024)
        *(float4*)&Ws[i] = *(const float4*)&W[i];
    const int base = blockIdx.x * 128;
    for (int i = tid; i < 2048; i += 256) {    // 128 rows x 16 float4s
        int r = i >> 4;
        int k = (i & 15) * 4;
        int row = base + r;
        float4 xv = (row < n) ? *(const float4*)&x[(size_t)row * 64 + k]
                              : make_float4(0.f, 0.f, 0.f, 0.f);
        xs[r][k] = xv.x; xs[r][k + 1] = xv.y; xs[r][k + 2] = xv.z; xs[r][k + 3] = xv.w;
    }
    __syncthreads();
    const int cg = tid & 7;    // cols cg*8..+8
    const int rg = tid >> 3;   // rows rg*4..+4
    float acc[4][8] = {};
#pragma unroll 4
    for (int k = 0; k < 64; ++k) {
        float w8[8];
        *(float4*)&w8[0] = *(const float4*)&Ws[k * 64 + cg * 8];
        *(float4*)&w8[4] = *(const float4*)&Ws[k * 64 + cg * 8 + 4];
        float x4[4];
#pragma unroll
        for (int rr = 0; rr < 4; ++rr) x4[rr] = xs[rg * 4 + rr][k];
#pragma unroll
        for (int rr = 0; rr < 4; ++rr)
#pragma unroll
            for (int cc = 0; cc < 8; ++cc)
                acc[rr][cc] = fmaf(x4[rr], w8[cc], acc[rr][cc]);
    }
#pragma unroll
    for (int rr = 0; rr < 4; ++rr) {
        int row = base + rg * 4 + rr;
        if (row >= n) break;
        float d = dis[row];
        union { __hip_bfloat16 h[8]; uint4 v; } p;
#pragma unroll
        for (int cc = 0; cc < 8; ++cc) p.h[cc] = __float2bfloat16(acc[rr][cc] * d);
        *(uint4*)&hs[(size_t)row * 64 + cg * 8] = p.v;
    }
}

// unpack 2 bf16 packed in a uint -> (lo, hi) floats
__device__ __forceinline__ float bflo(unsigned u) { return __uint_as_float(u << 16); }
__device__ __forceinline__ float bfhi(unsigned u) { return __uint_as_float(u & 0xFFFF0000u); }

// FUSED layer-1 gather + BN1 + ReLU + (act @ W2)*dis -> hs2 (bf16).
// HALF-WAVE per node: lanes gather features 2c,2c+1; act row staged in LDS;
// then each lane computes output feature c of the 64x32 matvec.
__global__ __launch_bounds__(256) void k_gather64_gemm32(
    const __hip_bfloat16* __restrict__ hs, const int* __restrict__ rowStart,
    const int* __restrict__ perm, const float* __restrict__ dis,
    const float* __restrict__ b, const float* __restrict__ g,
    const float* __restrict__ be, const float* __restrict__ m,
    const float* __restrict__ v, const float* __restrict__ W2,
    __hip_bfloat16* __restrict__ hs2, int n) {
    __shared__ float W2s[64 * 32];
    __shared__ float actS[8][64];                      // 8 nodes per block
    for (int i = threadIdx.x * 4; i < 2048; i += 1024)
        *(float4*)&W2s[i] = *(const float4*)&W2[i];
    __syncthreads();

    const unsigned* hsu = (const unsigned*)hs;         // [n][32] packed pairs
    int c = threadIdx.x & 31;
    int ln = threadIdx.x >> 5;                         // local node 0..7
    int node = (blockIdx.x * 256 + threadIdx.x) >> 5;
    if (node >= n) return;                             // uniform per half-wave
    int r0 = rowStart[node], r1 = rowStart[node + 1];
    float d = dis[node];
    unsigned su = hsu[(size_t)node * 32 + c];          // self term
    float a0 = bflo(su), a1 = bfhi(su);
    int e = r0;
    for (; e + 7 < r1; e += 8) {
        int s0 = perm[e],     s1 = perm[e + 1], s2 = perm[e + 2], s3 = perm[e + 3];
        int s4 = perm[e + 4], s5 = perm[e + 5], s6 = perm[e + 6], s7 = perm[e + 7];
        unsigned u0 = hsu[(size_t)s0 * 32 + c];
        unsigned u1 = hsu[(size_t)s1 * 32 + c];
        unsigned u2 = hsu[(size_t)s2 * 32 + c];
        unsigned u3 = hsu[(size_t)s3 * 32 + c];
        unsigned u4 = hsu[(size_t)s4 * 32 + c];
        unsigned u5 = hsu[(size_t)s5 * 32 + c];
        unsigned u6 = hsu[(size_t)s6 * 32 + c];
        unsigned u7 = hsu[(size_t)s7 * 32 + c];
        a0 += ((bflo(u0) + bflo(u1)) + (bflo(u2) + bflo(u3))) +
              ((bflo(u4) + bflo(u5)) + (bflo(u6) + bflo(u7)));
        a1 += ((bfhi(u0) + bfhi(u1)) + (bfhi(u2) + bfhi(u3))) +
              ((bfhi(u4) + bfhi(u5)) + (bfhi(u6) + bfhi(u7)));
    }
    for (; e + 3 < r1; e += 4) {
        int s0 = perm[e], s1 = perm[e + 1], s2 = perm[e + 2], s3 = perm[e + 3];
        unsigned u0 = hsu[(size_t)s0 * 32 + c];
        unsigned u1 = hsu[(size_t)s1 * 32 + c];
        unsigned u2 = hsu[(size_t)s2 * 32 + c];
        unsigned u3 = hsu[(size_t)s3 * 32 + c];
        a0 += (bflo(u0) + bflo(u1)) + (bflo(u2) + bflo(u3));
        a1 += (bfhi(u0) + bfhi(u1)) + (bfhi(u2) + bfhi(u3));
    }
    for (; e < r1; ++e) {
        unsigned u = hsu[(size_t)perm[e] * 32 + c];
        a0 += bflo(u); a1 += bfhi(u);
    }
    int f0 = 2 * c, f1 = 2 * c + 1;
    float sc0 = g[f0] * rsqrtf(v[f0] + 1e-5f);
    float sc1 = g[f1] * rsqrtf(v[f1] + 1e-5f);
    float sh0 = (b[f0] - m[f0]) * sc0 + be[f0];
    float sh1 = (b[f1] - m[f1]) * sc1 + be[f1];
    float y0 = fmaf(a0 * d, sc0, sh0);
    float y1 = fmaf(a1 * d, sc1, sh1);
    y0 = y0 > 0.f ? y0 : 0.f;
    y1 = y1 > 0.f ? y1 : 0.f;

    // stage act row in LDS (same-wave producer/consumer; lockstep ordering)
    *(float2*)&actS[ln][f0] = make_float2(y0, y1);

    // out[c] = sum_k act[k] * W2[k][c]  (broadcast LDS reads, conflict-free)
    float out = 0.f;
#pragma unroll
    for (int k2 = 0; k2 < 32; ++k2) {
        float2 a = *(const float2*)&actS[ln][2 * k2];
        out = fmaf(a.x, W2s[(2 * k2) * 32 + c], out);
        out = fmaf(a.y, W2s[(2 * k2 + 1) * 32 + c], out);
    }
    hs2[(size_t)node * 32 + c] = __float2bfloat16(out * d);
}

// F=32: QUARTER-WAVE per node, lane c in [0,16), 8-edge unroll.
__global__ __launch_bounds__(256) void k_gather32(
    const __hip_bfloat16* __restrict__ hs, const int* __restrict__ rowStart,
    const int* __restrict__ perm, const float* __restrict__ dis,
    const float* __restrict__ b, const float* __restrict__ g,
    const float* __restrict__ be, const float* __restrict__ m,
    const float* __restrict__ v, float* __restrict__ act, int n) {
    const unsigned* hsu = (const unsigned*)hs;         // [n][16] packed pairs
    int c = threadIdx.x & 15;
    int node = (blockIdx.x * 256 + threadIdx.x) >> 4;
    if (node >= n) return;
    int r0 = rowStart[node], r1 = rowStart[node + 1];
    float d = dis[node];
    unsigned su = hsu[(size_t)node * 16 + c];
    float a0 = bflo(su), a1 = bfhi(su);
    int e = r0;
    for (; e + 7 < r1; e += 8) {
        int s0 = perm[e],     s1 = perm[e + 1], s2 = perm[e + 2], s3 = perm[e + 3];
        int s4 = perm[e + 4], s5 = perm[e + 5], s6 = perm[e + 6], s7 = perm[e + 7];
        unsigned u0 = hsu[(size_t)s0 * 16 + c];
        unsigned u1 = hsu[(size_t)s1 * 16 + c];
        unsigned u2 = hsu[(size_t)s2 * 16 + c];
        unsigned u3 = hsu[(size_t)s3 * 16 + c];
        unsigned u4 = hsu[(size_t)s4 * 16 + c];
        unsigned u5 = hsu[(size_t)s5 * 16 + c];
        unsigned u6 = hsu[(size_t)s6 * 16 + c];
        unsigned u7 = hsu[(size_t)s7 * 16 + c];
        a0 += ((bflo(u0) + bflo(u1)) + (bflo(u2) + bflo(u3))) +
              ((bflo(u4) + bflo(u5)) + (bflo(u6) + bflo(u7)));
        a1 += ((bfhi(u0) + bfhi(u1)) + (bfhi(u2) + bfhi(u3))) +
              ((bfhi(u4) + bfhi(u5)) + (bfhi(u6) + bfhi(u7)));
    }
    for (; e + 3 < r1; e += 4) {
        int s0 = perm[e], s1 = perm[e + 1], s2 = perm[e + 2], s3 = perm[e + 3];
        unsigned u0 = hsu[(size_t)s0 * 16 + c];
        unsigned u1 = hsu[(size_t)s1 * 16 + c];
        unsigned u2 = hsu[(size_t)s2 * 16 + c];
        unsigned u3 = hsu[(size_t)s3 * 16 + c];
        a0 += (bflo(u0) + bflo(u1)) + (bflo(u2) + bflo(u3));
        a1 += (bfhi(u0) + bfhi(u1)) + (bfhi(u2) + bfhi(u3));
    }
    for (; e < r1; ++e) {
        unsigned u = hsu[(size_t)perm[e] * 16 + c];
        a0 += bflo(u); a1 += bfhi(u);
    }
    int f0 = 2 * c, f1 = 2 * c + 1;
    float sc0 = g[f0] * rsqrtf(v[f0] + 1e-5f);
    float sc1 = g[f1] * rsqrtf(v[f1] + 1e-5f);
    float sh0 = (b[f0] - m[f0]) * sc0 + be[f0];
    float sh1 = (b[f1] - m[f1]) * sc1 + be[f1];
    float y0 = fmaf(a0 * d, sc0, sh0);
    float y1 = fmaf(a1 * d, sc1, sh1);
    float2 o = {y0 > 0.f ? y0 : 0.f, y1 > 0.f ? y1 : 0.f};
    *(float2*)&act[(size_t)node * 32 + f0] = o;
}

// mean-pool: batch sorted -> run-length accumulate, few atomics.
__global__ __launch_bounds__(256) void k_pool(
    const float* __restrict__ act2, const int* __restrict__ batch,
    float* __restrict__ sums, float* __restrict__ cnt, int n) {
    int f = threadIdx.x & 31;
    int chunk = (blockIdx.x * blockDim.x + threadIdx.x) >> 5;
    int nchunks = (gridDim.x * blockDim.x) >> 5;
    int per = (n + nchunks - 1) / nchunks;
    int i0 = chunk * per;
    int i1 = min(n, i0 + per);
    if (i0 >= n) return;
    float acc = 0.f, c = 0.f;
    int cur = batch[i0];
    for (int i = i0; i < i1; ++i) {
        int bg = batch[i];
        if (bg != cur) {
            atomicAdd(&sums[(size_t)cur * 32 + f], acc);
            if (f == 0) atomicAdd(&cnt[cur], c);
            acc = 0.f; c = 0.f; cur = bg;
        }
        acc += act2[(size_t)i * 32 + f];
        c += 1.f;
    }
    atomicAdd(&sums[(size_t)cur * 32 + f], acc);
    if (f == 0) atomicAdd(&cnt[cur], c);
}

__global__ void k_mlp(const float* __restrict__ sums, const float* __restrict__ cnt,
                      const float* __restrict__ Wc1, const float* __restrict__ bc1,
                      const float* __restrict__ Wc2, const float* __restrict__ bc2,
                      float* __restrict__ out, int G) {
    int g = blockIdx.x * blockDim.x + threadIdx.x;
    if (g >= G) return;
    float c = cnt[g];
    c = c < 1.f ? 1.f : c;
    float inv = 1.f / c;
    float z[32];
#pragma unroll
    for (int j = 0; j < 32; ++j) z[j] = sums[(size_t)g * 32 + j] * inv;
    float o0 = bc2[0], o1 = bc2[1];
#pragma unroll
    for (int k = 0; k < 16; ++k) {
        float t = bc1[k];
#pragma unroll
        for (int j = 0; j < 32; ++j) t = fmaf(z[j], Wc1[j * 16 + k], t);
        t = t > 0.f ? t : 0.f;
        o0 = fmaf(t, Wc2[k * 2 + 0], o0);
        o1 = fmaf(t, Wc2[k * 2 + 1], o1);
    }
    out[g * 2 + 0] = o0;
    out[g * 2 + 1] = o1;
}

extern "C" void kernel_launch(void* const* d_in, const int* in_sizes, int n_in,
                              void* d_out, int out_size, void* d_ws, size_t ws_size,
                              hipStream_t stream) {
    const float* x   = (const float*)d_in[0];
    const int* ei    = (const int*)d_in[1];
    const int* batch = (const int*)d_in[2];
    const float* W1  = (const float*)d_in[3];
    const float* b1  = (const float*)d_in[4];
    const float* g1  = (const float*)d_in[5];
    const float* be1 = (const float*)d_in[6];
    const float* m1  = (const float*)d_in[7];
    const float* v1  = (const float*)d_in[8];
    const float* W2  = (const float*)d_in[9];
    const float* b2  = (const float*)d_in[10];
    const float* g2  = (const float*)d_in[11];
    const float* be2 = (const float*)d_in[12];
    const float* m2  = (const float*)d_in[13];
    const float* v2  = (const float*)d_in[14];
    const float* Wc1 = (const float*)d_in[15];
    const float* bc1 = (const float*)d_in[16];
    const float* Wc2 = (const float*)d_in[17];
    const float* bc2 = (const float*)d_in[18];

    const int n = in_sizes[2];          // 100000 nodes
    const int E = in_sizes[1] / 2;      // 1000000 edges
    const int G = out_size / 2;         // 500 graphs
    const int* srcI = ei;
    const int* dstI = ei + E;
    const int NB = (n + 255) >> 8;      // buckets of 256 nodes

    // ---- workspace layout (256 B aligned segments) ----
    char* p = (char*)d_ws;
    auto alloc = [&](size_t bytes) {
        char* r = p;
        p += (bytes + 255) & ~(size_t)255;
        return r;
    };
    float*    dis          = (float*)alloc((size_t)n * 4);
    int*      bucketCnt    = (int*)alloc(512 * 4);
    int*      bucketStart  = (int*)alloc(513 * 4);
    int*      bucketCursor = (int*)alloc(512 * 4);
    unsigned* pairs        = (unsigned*)alloc((size_t)E * 4);
    int*      perm         = (int*)alloc((size_t)E * 4);
    int*      rowStart     = (int*)alloc(((size_t)n + 1) * 4);
    __hip_bfloat16* hs1b   = (__hip_bfloat16*)alloc((size_t)64 * n * 2);
    __hip_bfloat16* hs2b   = (__hip_bfloat16*)alloc((size_t)32 * n * 2);
    float*    act2         = (float*)alloc((size_t)32 * n * 4);
    float*    sums         = (float*)alloc((size_t)32 * G * 4 + (size_t)G * 4);
    float*    cntG         = sums + (size_t)32 * G;

    const int NT = 256;
    const int nbE = (E + CHUNK - 1) / CHUNK;
    const int nSums = G * 33;           // sums + cntG contiguous

    // CSR build (bucketed counting sort), reused by both layers
    k_zero_misc<<<(512 + nSums + NT - 1) / NT, NT, 0, stream>>>(bucketCnt, sums, nSums);
    k_hist<<<nbE, NT, 0, stream>>>(dstI, bucketCnt, E);
    k_scan512<<<1, 512, 0, stream>>>(bucketCnt, bucketStart, bucketCursor);
    k_binpairs<<<nbE, NT, 0, stream>>>(srcI, dstI, bucketCursor, pairs, E);
    k_csr<<<NB, NT, 0, stream>>>(pairs, bucketStart, rowStart, dis, perm, n, E);

    // layer 1 (+ fused layer-2 GEMM)
    k_gemm64<<<(n + 127) / 128, NT, 0, stream>>>(x, W1, dis, hs1b, n);
    k_gather64_gemm32<<<(n * 32 + NT - 1) / NT, NT, 0, stream>>>(
        hs1b, rowStart, perm, dis, b1, g1, be1, m1, v1, W2, hs2b, n);

    // layer 2 gather
    k_gather32<<<(n * 16 + NT - 1) / NT, NT, 0, stream>>>(hs2b, rowStart, perm, dis,
                                                          b2, g2, be2, m2, v2, act2, n);
    // pool
    k_pool<<<1024, NT, 0, stream>>>(act2, batch, sums, cntG, n);

    // classifier
    k_mlp<<<(G + NT - 1) / NT, NT, 0, stream>>>(sums, cntG, Wc1, bc1, Wc2, bc2,
                                                (float*)d_out, G);
}

// Round 11
// 157.895 us; speedup vs baseline: 1.0759x; 1.0759x over previous
//
#include <hip/hip_runtime.h>
#include <hip/hip_bf16.h>

// ---------------------------------------------------------------------------
// GCN forward: 2x (GCNConv -> BN(eval) -> ReLU) -> mean-pool -> MLP
// N=100000 nodes, E=1e6 edges, feats 64->64->32, 500 graphs, out [500,2] f32
// R1: scatter-atomics -> CSR-by-dst gather; hs pre-scaled by dis[row].
// R2: self-loop fix.  R3: LDS-tiled GEMMs.  R4: hs bf16.  R5: bucket CSR.
// R6: sub-wave gathers.  R7: pool grid.  R8: 8-edge unroll.  R9: gemm32 fused.
// R10: hs1 stored FP8 e4m3 (HW cvt_pk): row = 64B = ONE cache line/edge,
//      table 6.4MB (vs 12.8) -> higher per-XCD L2 hit rate. Fused gather
//      restructured to quarter-wave/node (4 fp8 feats per lane, 4 edges per
//      wave-instr). actS stride 68 = conflict-free matvec. hs2 stays bf16.
// ---------------------------------------------------------------------------

#define CHUNK 4096

typedef float floatx2 __attribute__((ext_vector_type(2)));

// zero bucketCnt[512] and sums/cntG (nSums floats)
__global__ void k_zero_misc(int* __restrict__ bucketCnt, float* __restrict__ sums,
                            int nSums) {
    int i = blockIdx.x * blockDim.x + threadIdx.x;
    if (i < 512) bucketCnt[i] = 0;
    int j = i - 512;
    if (j >= 0 && j < nSums) sums[j] = 0.f;
}

// LDS-aggregated histogram of dst>>8 into bucketCnt[512]
__global__ __launch_bounds__(256) void k_hist(const int* __restrict__ dst,
                                              int* __restrict__ bucketCnt, int E) {
    __shared__ int lh[512];
    for (int i = threadIdx.x; i < 512; i += 256) lh[i] = 0;
    __syncthreads();
    int base = blockIdx.x * CHUNK;
    for (int i = threadIdx.x; i < CHUNK; i += 256) {
        int e = base + i;
        if (e < E) atomicAdd(&lh[dst[e] >> 8], 1);
    }
    __syncthreads();
    for (int i = threadIdx.x; i < 512; i += 256)
        if (lh[i]) atomicAdd(&bucketCnt[i], lh[i]);
}

// exclusive scan of bucketCnt -> bucketStart, bucketCursor (one block, 512 thr)
__global__ void k_scan512(const int* __restrict__ bucketCnt,
                          int* __restrict__ bucketStart,
                          int* __restrict__ bucketCursor) {
    __shared__ int s[512];
    int tid = threadIdx.x;
    int v = bucketCnt[tid];
    s[tid] = v;
    __syncthreads();
    for (int off = 1; off < 512; off <<= 1) {
        int t = (tid >= off) ? s[tid - off] : 0;
        __syncthreads();
        s[tid] += t;
        __syncthreads();
    }
    int excl = s[tid] - v;
    bucketStart[tid] = excl;
    bucketCursor[tid] = excl;
    if (tid == 511) bucketStart[512] = s[511];   // = E
}

// scatter packed (src<<8 | dst&255) into bucket regions, block-aggregated
__global__ __launch_bounds__(256) void k_binpairs(
    const int* __restrict__ src, const int* __restrict__ dst,
    int* __restrict__ bucketCursor, unsigned* __restrict__ pairs, int E) {
    __shared__ int lh[512];
    __shared__ int lbase[512];
    for (int i = threadIdx.x; i < 512; i += 256) lh[i] = 0;
    __syncthreads();
    int base = blockIdx.x * CHUNK;
    for (int i = threadIdx.x; i < CHUNK; i += 256) {
        int e = base + i;
        if (e < E) atomicAdd(&lh[dst[e] >> 8], 1);
    }
    __syncthreads();
    for (int i = threadIdx.x; i < 512; i += 256) {
        int c = lh[i];
        lbase[i] = c ? atomicAdd(&bucketCursor[i], c) : 0;
        lh[i] = 0;   // reuse as local cursor
    }
    __syncthreads();
    for (int i = threadIdx.x; i < CHUNK; i += 256) {
        int e = base + i;
        if (e < E) {
            int d = dst[e];
            int b = d >> 8;
            int r = atomicAdd(&lh[b], 1);
            pairs[lbase[b] + r] = ((unsigned)src[e] << 8) | (unsigned)(d & 255);
        }
    }
}

// per-bucket (256 nodes) LDS counting sort -> rowStart, dis, perm
__global__ __launch_bounds__(256) void k_csr(
    const unsigned* __restrict__ pairs, const int* __restrict__ bucketStart,
    int* __restrict__ rowStart, float* __restrict__ dis, int* __restrict__ perm,
    int n, int E) {
    __shared__ int cnt[256];
    __shared__ int s[256];
    __shared__ int cur[256];
    int b = blockIdx.x, tid = threadIdx.x;
    int r0 = bucketStart[b], r1 = bucketStart[b + 1];
    cnt[tid] = 0;
    __syncthreads();
    for (int i = r0 + tid; i < r1; i += 256) atomicAdd(&cnt[pairs[i] & 255], 1);
    __syncthreads();
    int v = cnt[tid];
    s[tid] = v;
    __syncthreads();
    for (int off = 1; off < 256; off <<= 1) {
        int t = (tid >= off) ? s[tid - off] : 0;
        __syncthreads();
        s[tid] += t;
        __syncthreads();
    }
    int excl = s[tid] - v;
    int node = b * 256 + tid;
    if (node < n) {
        rowStart[node] = r0 + excl;
        dis[node] = rsqrtf((float)v + 1.0f);   // in-degree + self-loop
    }
    if (b == 0 && tid == 0) rowStart[n] = E;
    cur[tid] = excl;
    __syncthreads();
    for (int i = r0 + tid; i < r1; i += 256) {
        unsigned p = pairs[i];
        int lo = p & 255;
        int slot = atomicAdd(&cur[lo], 1);
        perm[r0 + slot] = (int)(p >> 8);
    }
}

// hs = fp8((x @ W) * dis[row]). Tile 128x64, thread tile 4 rows x 8 cols.
__global__ __launch_bounds__(256) void k_gemm64(
    const float* __restrict__ x, const float* __restrict__ W,
    const float* __restrict__ dis, unsigned char* __restrict__ hs8, int n) {
    __shared__ float Ws[64 * 64];
    __shared__ float xs[128][65];          // odd stride: conflict-free
    const int tid = threadIdx.x;
    for (int i = tid * 4; i < 4096; i += 1024)
        *(float4*)&Ws[i] = *(const float4*)&W[i];
    const int base = blockIdx.x * 128;
    for (int i = tid; i < 2048; i += 256) {    // 128 rows x 16 float4s
        int r = i >> 4;
        int k = (i & 15) * 4;
        int row = base + r;
        float4 xv = (row < n) ? *(const float4*)&x[(size_t)row * 64 + k]
                              : make_float4(0.f, 0.f, 0.f, 0.f);
        xs[r][k] = xv.x; xs[r][k + 1] = xv.y; xs[r][k + 2] = xv.z; xs[r][k + 3] = xv.w;
    }
    __syncthreads();
    const int cg = tid & 7;    // cols cg*8..+8
    const int rg = tid >> 3;   // rows rg*4..+4
    float acc[4][8] = {};
#pragma unroll 4
    for (int k = 0; k < 64; ++k) {
        float w8[8];
        *(float4*)&w8[0] = *(const float4*)&Ws[k * 64 + cg * 8];
        *(float4*)&w8[4] = *(const float4*)&Ws[k * 64 + cg * 8 + 4];
        float x4[4];
#pragma unroll
        for (int rr = 0; rr < 4; ++rr) x4[rr] = xs[rg * 4 + rr][k];
#pragma unroll
        for (int rr = 0; rr < 4; ++rr)
#pragma unroll
            for (int cc = 0; cc < 8; ++cc)
                acc[rr][cc] = fmaf(x4[rr], w8[cc], acc[rr][cc]);
    }
#pragma unroll
    for (int rr = 0; rr < 4; ++rr) {
        int row = base + rg * 4 + rr;
        if (row >= n) break;
        float d = dis[row];
        float v0 = acc[rr][0] * d, v1 = acc[rr][1] * d;
        float v2 = acc[rr][2] * d, v3 = acc[rr][3] * d;
        float v4 = acc[rr][4] * d, v5 = acc[rr][5] * d;
        float v6 = acc[rr][6] * d, v7 = acc[rr][7] * d;
        int q0 = __builtin_amdgcn_cvt_pk_fp8_f32(v0, v1, 0, false);
        q0 = __builtin_amdgcn_cvt_pk_fp8_f32(v2, v3, q0, true);
        int q1 = __builtin_amdgcn_cvt_pk_fp8_f32(v4, v5, 0, false);
        q1 = __builtin_amdgcn_cvt_pk_fp8_f32(v6, v7, q1, true);
        uint2 q = {(unsigned)q0, (unsigned)q1};
        *(uint2*)&hs8[(size_t)row * 64 + cg * 8] = q;
    }
}

// FUSED layer-1 gather(fp8) + BN1 + ReLU + (act @ W2)*dis -> hs2 (bf16).
// QUARTER-WAVE per node: lane c in [0,16) gathers features 4c..4c+3 (one 4B
// load = 4 fp8 per edge). act row staged in LDS (stride 68, conflict-free);
// each lane then computes output cols c and c+16 of the 64x32 matvec.
__global__ __launch_bounds__(256) void k_gather64f8_gemm32(
    const unsigned char* __restrict__ hs8, const int* __restrict__ rowStart,
    const int* __restrict__ perm, const float* __restrict__ dis,
    const float* __restrict__ b, const float* __restrict__ g,
    const float* __restrict__ be, const float* __restrict__ m,
    const float* __restrict__ v, const float* __restrict__ W2,
    __hip_bfloat16* __restrict__ hs2, int n) {
    __shared__ float W2s[64 * 32];
    __shared__ float actS[16][68];                     // stride 68: (ln*4+k)%32
    for (int i = threadIdx.x * 4; i < 2048; i += 1024)
        *(float4*)&W2s[i] = *(const float4*)&W2[i];
    __syncthreads();

    const unsigned* hsu = (const unsigned*)hs8;        // [n][16] words of 4 fp8
    int c = threadIdx.x & 15;
    int ln = threadIdx.x >> 4;                         // local node 0..15
    int node = (blockIdx.x * 256 + threadIdx.x) >> 4;
    if (node >= n) return;                             // uniform per quarter-wave
    int r0 = rowStart[node], r1 = rowStart[node + 1];
    float d = dis[node];
    float a0, a1, a2, a3;
    {
        unsigned su = hsu[(size_t)node * 16 + c];      // self term
        floatx2 lo = __builtin_amdgcn_cvt_pk_f32_fp8(su, false);
        floatx2 hi = __builtin_amdgcn_cvt_pk_f32_fp8(su, true);
        a0 = lo[0]; a1 = lo[1]; a2 = hi[0]; a3 = hi[1];
    }
    int e = r0;
    for (; e + 7 < r1; e += 8) {
        int s0 = perm[e],     s1 = perm[e + 1], s2 = perm[e + 2], s3 = perm[e + 3];
        int s4 = perm[e + 4], s5 = perm[e + 5], s6 = perm[e + 6], s7 = perm[e + 7];
        unsigned u0 = hsu[(size_t)s0 * 16 + c];
        unsigned u1 = hsu[(size_t)s1 * 16 + c];
        unsigned u2 = hsu[(size_t)s2 * 16 + c];
        unsigned u3 = hsu[(size_t)s3 * 16 + c];
        unsigned u4 = hsu[(size_t)s4 * 16 + c];
        unsigned u5 = hsu[(size_t)s5 * 16 + c];
        unsigned u6 = hsu[(size_t)s6 * 16 + c];
        unsigned u7 = hsu[(size_t)s7 * 16 + c];
#pragma unroll
        for (int j = 0; j < 8; ++j) {
            unsigned u = j == 0 ? u0 : j == 1 ? u1 : j == 2 ? u2 : j == 3 ? u3
                       : j == 4 ? u4 : j == 5 ? u5 : j == 6 ? u6 : u7;
            floatx2 lo = __builtin_amdgcn_cvt_pk_f32_fp8(u, false);
            floatx2 hi = __builtin_amdgcn_cvt_pk_f32_fp8(u, true);
            a0 += lo[0]; a1 += lo[1]; a2 += hi[0]; a3 += hi[1];
        }
    }
    for (; e < r1; ++e) {
        unsigned u = hsu[(size_t)perm[e] * 16 + c];
        floatx2 lo = __builtin_amdgcn_cvt_pk_f32_fp8(u, false);
        floatx2 hi = __builtin_amdgcn_cvt_pk_f32_fp8(u, true);
        a0 += lo[0]; a1 += lo[1]; a2 += hi[0]; a3 += hi[1];
    }
    int f = 4 * c;
    float4 gv = *(const float4*)&g[f];
    float4 vv = *(const float4*)&v[f];
    float4 bv = *(const float4*)&b[f];
    float4 mv = *(const float4*)&m[f];
    float4 bev = *(const float4*)&be[f];
    float sc0 = gv.x * rsqrtf(vv.x + 1e-5f), sc1 = gv.y * rsqrtf(vv.y + 1e-5f);
    float sc2 = gv.z * rsqrtf(vv.z + 1e-5f), sc3 = gv.w * rsqrtf(vv.w + 1e-5f);
    float y0 = fmaf(a0 * d, sc0, (bv.x - mv.x) * sc0 + bev.x);
    float y1 = fmaf(a1 * d, sc1, (bv.y - mv.y) * sc1 + bev.y);
    float y2 = fmaf(a2 * d, sc2, (bv.z - mv.z) * sc2 + bev.z);
    float y3 = fmaf(a3 * d, sc3, (bv.w - mv.w) * sc3 + bev.w);
    float4 yv = {y0 > 0.f ? y0 : 0.f, y1 > 0.f ? y1 : 0.f,
                 y2 > 0.f ? y2 : 0.f, y3 > 0.f ? y3 : 0.f};
    *(float4*)&actS[ln][f] = yv;   // same-wave producer/consumer (lockstep)

    // out[c], out[c+16] = sum_k act[k] * W2[k][col]
    float o0 = 0.f, o1 = 0.f;
#pragma unroll
    for (int k = 0; k < 64; ++k) {
        float a = actS[ln][k];
        o0 = fmaf(a, W2s[k * 32 + c], o0);
        o1 = fmaf(a, W2s[k * 32 + c + 16], o1);
    }
    hs2[(size_t)node * 32 + c] = __float2bfloat16(o0 * d);
    hs2[(size_t)node * 32 + c + 16] = __float2bfloat16(o1 * d);
}

// unpack 2 bf16 packed in a uint -> (lo, hi) floats
__device__ __forceinline__ float bflo(unsigned u) { return __uint_as_float(u << 16); }
__device__ __forceinline__ float bfhi(unsigned u) { return __uint_as_float(u & 0xFFFF0000u); }

// F=32: QUARTER-WAVE per node, lane c in [0,16), 8-edge unroll. (bf16 rows)
__global__ __launch_bounds__(256) void k_gather32(
    const __hip_bfloat16* __restrict__ hs, const int* __restrict__ rowStart,
    const int* __restrict__ perm, const float* __restrict__ dis,
    const float* __restrict__ b, const float* __restrict__ g,
    const float* __restrict__ be, const float* __restrict__ m,
    const float* __restrict__ v, float* __restrict__ act, int n) {
    const unsigned* hsu = (const unsigned*)hs;         // [n][16] packed pairs
    int c = threadIdx.x & 15;
    int node = (blockIdx.x * 256 + threadIdx.x) >> 4;
    if (node >= n) return;
    int r0 = rowStart[node], r1 = rowStart[node + 1];
    float d = dis[node];
    unsigned su = hsu[(size_t)node * 16 + c];
    float a0 = bflo(su), a1 = bfhi(su);
    int e = r0;
    for (; e + 7 < r1; e += 8) {
        int s0 = perm[e],     s1 = perm[e + 1], s2 = perm[e + 2], s3 = perm[e + 3];
        int s4 = perm[e + 4], s5 = perm[e + 5], s6 = perm[e + 6], s7 = perm[e + 7];
        unsigned u0 = hsu[(size_t)s0 * 16 + c];
        unsigned u1 = hsu[(size_t)s1 * 16 + c];
        unsigned u2 = hsu[(size_t)s2 * 16 + c];
        unsigned u3 = hsu[(size_t)s3 * 16 + c];
        unsigned u4 = hsu[(size_t)s4 * 16 + c];
        unsigned u5 = hsu[(size_t)s5 * 16 + c];
        unsigned u6 = hsu[(size_t)s6 * 16 + c];
        unsigned u7 = hsu[(size_t)s7 * 16 + c];
        a0 += ((bflo(u0) + bflo(u1)) + (bflo(u2) + bflo(u3))) +
              ((bflo(u4) + bflo(u5)) + (bflo(u6) + bflo(u7)));
        a1 += ((bfhi(u0) + bfhi(u1)) + (bfhi(u2) + bfhi(u3))) +
              ((bfhi(u4) + bfhi(u5)) + (bfhi(u6) + bfhi(u7)));
    }
    for (; e < r1; ++e) {
        unsigned u = hsu[(size_t)perm[e] * 16 + c];
        a0 += bflo(u); a1 += bfhi(u);
    }
    int f0 = 2 * c, f1 = 2 * c + 1;
    float sc0 = g[f0] * rsqrtf(v[f0] + 1e-5f);
    float sc1 = g[f1] * rsqrtf(v[f1] + 1e-5f);
    float sh0 = (b[f0] - m[f0]) * sc0 + be[f0];
    float sh1 = (b[f1] - m[f1]) * sc1 + be[f1];
    float y0 = fmaf(a0 * d, sc0, sh0);
    float y1 = fmaf(a1 * d, sc1, sh1);
    float2 o = {y0 > 0.f ? y0 : 0.f, y1 > 0.f ? y1 : 0.f};
    *(float2*)&act[(size_t)node * 32 + f0] = o;
}

// mean-pool: batch sorted -> run-length accumulate, few atomics.
__global__ __launch_bounds__(256) void k_pool(
    const float* __restrict__ act2, const int* __restrict__ batch,
    float* __restrict__ sums, float* __restrict__ cnt, int n) {
    int f = threadIdx.x & 31;
    int chunk = (blockIdx.x * blockDim.x + threadIdx.x) >> 5;
    int nchunks = (gridDim.x * blockDim.x) >> 5;
    int per = (n + nchunks - 1) / nchunks;
    int i0 = chunk * per;
    int i1 = min(n, i0 + per);
    if (i0 >= n) return;
    float acc = 0.f, c = 0.f;
    int cur = batch[i0];
    for (int i = i0; i < i1; ++i) {
        int bg = batch[i];
        if (bg != cur) {
            atomicAdd(&sums[(size_t)cur * 32 + f], acc);
            if (f == 0) atomicAdd(&cnt[cur], c);
            acc = 0.f; c = 0.f; cur = bg;
        }
        acc += act2[(size_t)i * 32 + f];
        c += 1.f;
    }
    atomicAdd(&sums[(size_t)cur * 32 + f], acc);
    if (f == 0) atomicAdd(&cnt[cur], c);
}

__global__ void k_mlp(const float* __restrict__ sums, const float* __restrict__ cnt,
                      const float* __restrict__ Wc1, const float* __restrict__ bc1,
                      const float* __restrict__ Wc2, const float* __restrict__ bc2,
                      float* __restrict__ out, int G) {
    int g = blockIdx.x * blockDim.x + threadIdx.x;
    if (g >= G) return;
    float c = cnt[g];
    c = c < 1.f ? 1.f : c;
    float inv = 1.f / c;
    float z[32];
#pragma unroll
    for (int j = 0; j < 32; ++j) z[j] = sums[(size_t)g * 32 + j] * inv;
    float o0 = bc2[0], o1 = bc2[1];
#pragma unroll
    for (int k = 0; k < 16; ++k) {
        float t = bc1[k];
#pragma unroll
        for (int j = 0; j < 32; ++j) t = fmaf(z[j], Wc1[j * 16 + k], t);
        t = t > 0.f ? t : 0.f;
        o0 = fmaf(t, Wc2[k * 2 + 0], o0);
        o1 = fmaf(t, Wc2[k * 2 + 1], o1);
    }
    out[g * 2 + 0] = o0;
    out[g * 2 + 1] = o1;
}

extern "C" void kernel_launch(void* const* d_in, const int* in_sizes, int n_in,
                              void* d_out, int out_size, void* d_ws, size_t ws_size,
                              hipStream_t stream) {
    const float* x   = (const float*)d_in[0];
    const int* ei    = (const int*)d_in[1];
    const int* batch = (const int*)d_in[2];
    const float* W1  = (const float*)d_in[3];
    const float* b1  = (const float*)d_in[4];
    const float* g1  = (const float*)d_in[5];
    const float* be1 = (const float*)d_in[6];
    const float* m1  = (const float*)d_in[7];
    const float* v1  = (const float*)d_in[8];
    const float* W2  = (const float*)d_in[9];
    const float* b2  = (const float*)d_in[10];
    const float* g2  = (const float*)d_in[11];
    const float* be2 = (const float*)d_in[12];
    const float* m2  = (const float*)d_in[13];
    const float* v2  = (const float*)d_in[14];
    const float* Wc1 = (const float*)d_in[15];
    const float* bc1 = (const float*)d_in[16];
    const float* Wc2 = (const float*)d_in[17];
    const float* bc2 = (const float*)d_in[18];

    const int n = in_sizes[2];          // 100000 nodes
    const int E = in_sizes[1] / 2;      // 1000000 edges
    const int G = out_size / 2;         // 500 graphs
    const int* srcI = ei;
    const int* dstI = ei + E;
    const int NB = (n + 255) >> 8;      // buckets of 256 nodes

    // ---- workspace layout (256 B aligned segments) ----
    char* p = (char*)d_ws;
    auto alloc = [&](size_t bytes) {
        char* r = p;
        p += (bytes + 255) & ~(size_t)255;
        return r;
    };
    float*    dis          = (float*)alloc((size_t)n * 4);
    int*      bucketCnt    = (int*)alloc(512 * 4);
    int*      bucketStart  = (int*)alloc(513 * 4);
    int*      bucketCursor = (int*)alloc(512 * 4);
    unsigned* pairs        = (unsigned*)alloc((size_t)E * 4);
    int*      perm         = (int*)alloc((size_t)E * 4);
    int*      rowStart     = (int*)alloc(((size_t)n + 1) * 4);
    unsigned char* hs1f8   = (unsigned char*)alloc((size_t)64 * n);
    __hip_bfloat16* hs2b   = (__hip_bfloat16*)alloc((size_t)32 * n * 2);
    float*    act2         = (float*)alloc((size_t)32 * n * 4);
    float*    sums         = (float*)alloc((size_t)32 * G * 4 + (size_t)G * 4);
    float*    cntG         = sums + (size_t)32 * G;

    const int NT = 256;
    const int nbE = (E + CHUNK - 1) / CHUNK;
    const int nSums = G * 33;           // sums + cntG contiguous

    // CSR build (bucketed counting sort), reused by both layers
    k_zero_misc<<<(512 + nSums + NT - 1) / NT, NT, 0, stream>>>(bucketCnt, sums, nSums);
    k_hist<<<nbE, NT, 0, stream>>>(dstI, bucketCnt, E);
    k_scan512<<<1, 512, 0, stream>>>(bucketCnt, bucketStart, bucketCursor);
    k_binpairs<<<nbE, NT, 0, stream>>>(srcI, dstI, bucketCursor, pairs, E);
    k_csr<<<NB, NT, 0, stream>>>(pairs, bucketStart, rowStart, dis, perm, n, E);

    // layer 1 (fp8 hs) + fused layer-2 GEMM
    k_gemm64<<<(n + 127) / 128, NT, 0, stream>>>(x, W1, dis, hs1f8, n);
    k_gather64f8_gemm32<<<(n * 16 + NT - 1) / NT, NT, 0, stream>>>(
        hs1f8, rowStart, perm, dis, b1, g1, be1, m1, v1, W2, hs2b, n);

    // layer 2 gather
    k_gather32<<<(n * 16 + NT - 1) / NT, NT, 0, stream>>>(hs2b, rowStart, perm, dis,
                                                          b2, g2, be2, m2, v2, act2, n);
    // pool
    k_pool<<<1024, NT, 0, stream>>>(act2, batch, sums, cntG, n);

    // classifier
    k_mlp<<<(G + NT - 1) / NT, NT, 0, stream>>>(sums, cntG, Wc1, bc1, Wc2, bc2,
                                                (float*)d_out, G);
}

// Round 12
// 150.034 us; speedup vs baseline: 1.1322x; 1.0524x over previous
//
#include <hip/hip_runtime.h>
#include <hip/hip_bf16.h>

// ---------------------------------------------------------------------------
// GCN forward: 2x (GCNConv -> BN(eval) -> ReLU) -> mean-pool -> MLP
// N=100000 nodes, E=1e6 edges, feats 64->64->32, 500 graphs, out [500,2] f32
// R1: scatter->CSR gather; hs pre-scaled by dis.  R2: self-loop fix.
// R3: LDS-tiled GEMMs.  R4: bf16 hs.  R5: bucket-counting-sort CSR.
// R6: sub-wave gathers.  R7: pool grid.  R8: 8-edge unroll.  R9: gemm32 fused.
// R10: hs1 fp8 e4m3 (64B rows, 6.4MB table).
// R11: hs2 ALSO fp8 (32B rows, 3.2MB table -> fits one per-XCD L2);
//      gather32 -> eighth-wave/node (8 edges per wave-instr); fused kernel
//      epilogue packs cols 2c,2c+1 into one ushort (cvt_pk) store.
// ---------------------------------------------------------------------------

#define CHUNK 4096

typedef float floatx2 __attribute__((ext_vector_type(2)));

// zero bucketCnt[512] and sums/cntG (nSums floats)
__global__ void k_zero_misc(int* __restrict__ bucketCnt, float* __restrict__ sums,
                            int nSums) {
    int i = blockIdx.x * blockDim.x + threadIdx.x;
    if (i < 512) bucketCnt[i] = 0;
    int j = i - 512;
    if (j >= 0 && j < nSums) sums[j] = 0.f;
}

// LDS-aggregated histogram of dst>>8 into bucketCnt[512]
__global__ __launch_bounds__(256) void k_hist(const int* __restrict__ dst,
                                              int* __restrict__ bucketCnt, int E) {
    __shared__ int lh[512];
    for (int i = threadIdx.x; i < 512; i += 256) lh[i] = 0;
    __syncthreads();
    int base = blockIdx.x * CHUNK;
    for (int i = threadIdx.x; i < CHUNK; i += 256) {
        int e = base + i;
        if (e < E) atomicAdd(&lh[dst[e] >> 8], 1);
    }
    __syncthreads();
    for (int i = threadIdx.x; i < 512; i += 256)
        if (lh[i]) atomicAdd(&bucketCnt[i], lh[i]);
}

// exclusive scan of bucketCnt -> bucketStart, bucketCursor (one block, 512 thr)
__global__ void k_scan512(const int* __restrict__ bucketCnt,
                          int* __restrict__ bucketStart,
                          int* __restrict__ bucketCursor) {
    __shared__ int s[512];
    int tid = threadIdx.x;
    int v = bucketCnt[tid];
    s[tid] = v;
    __syncthreads();
    for (int off = 1; off < 512; off <<= 1) {
        int t = (tid >= off) ? s[tid - off] : 0;
        __syncthreads();
        s[tid] += t;
        __syncthreads();
    }
    int excl = s[tid] - v;
    bucketStart[tid] = excl;
    bucketCursor[tid] = excl;
    if (tid == 511) bucketStart[512] = s[511];   // = E
}

// scatter packed (src<<8 | dst&255) into bucket regions, block-aggregated
__global__ __launch_bounds__(256) void k_binpairs(
    const int* __restrict__ src, const int* __restrict__ dst,
    int* __restrict__ bucketCursor, unsigned* __restrict__ pairs, int E) {
    __shared__ int lh[512];
    __shared__ int lbase[512];
    for (int i = threadIdx.x; i < 512; i += 256) lh[i] = 0;
    __syncthreads();
    int base = blockIdx.x * CHUNK;
    for (int i = threadIdx.x; i < CHUNK; i += 256) {
        int e = base + i;
        if (e < E) atomicAdd(&lh[dst[e] >> 8], 1);
    }
    __syncthreads();
    for (int i = threadIdx.x; i < 512; i += 256) {
        int c = lh[i];
        lbase[i] = c ? atomicAdd(&bucketCursor[i], c) : 0;
        lh[i] = 0;   // reuse as local cursor
    }
    __syncthreads();
    for (int i = threadIdx.x; i < CHUNK; i += 256) {
        int e = base + i;
        if (e < E) {
            int d = dst[e];
            int b = d >> 8;
            int r = atomicAdd(&lh[b], 1);
            pairs[lbase[b] + r] = ((unsigned)src[e] << 8) | (unsigned)(d & 255);
        }
    }
}

// per-bucket (256 nodes) LDS counting sort -> rowStart, dis, perm
__global__ __launch_bounds__(256) void k_csr(
    const unsigned* __restrict__ pairs, const int* __restrict__ bucketStart,
    int* __restrict__ rowStart, float* __restrict__ dis, int* __restrict__ perm,
    int n, int E) {
    __shared__ int cnt[256];
    __shared__ int s[256];
    __shared__ int cur[256];
    int b = blockIdx.x, tid = threadIdx.x;
    int r0 = bucketStart[b], r1 = bucketStart[b + 1];
    cnt[tid] = 0;
    __syncthreads();
    for (int i = r0 + tid; i < r1; i += 256) atomicAdd(&cnt[pairs[i] & 255], 1);
    __syncthreads();
    int v = cnt[tid];
    s[tid] = v;
    __syncthreads();
    for (int off = 1; off < 256; off <<= 1) {
        int t = (tid >= off) ? s[tid - off] : 0;
        __syncthreads();
        s[tid] += t;
        __syncthreads();
    }
    int excl = s[tid] - v;
    int node = b * 256 + tid;
    if (node < n) {
        rowStart[node] = r0 + excl;
        dis[node] = rsqrtf((float)v + 1.0f);   // in-degree + self-loop
    }
    if (b == 0 && tid == 0) rowStart[n] = E;
    cur[tid] = excl;
    __syncthreads();
    for (int i = r0 + tid; i < r1; i += 256) {
        unsigned p = pairs[i];
        int lo = p & 255;
        int slot = atomicAdd(&cur[lo], 1);
        perm[r0 + slot] = (int)(p >> 8);
    }
}

// hs = fp8((x @ W) * dis[row]). Tile 128x64, thread tile 4 rows x 8 cols.
__global__ __launch_bounds__(256) void k_gemm64(
    const float* __restrict__ x, const float* __restrict__ W,
    const float* __restrict__ dis, unsigned char* __restrict__ hs8, int n) {
    __shared__ float Ws[64 * 64];
    __shared__ float xs[128][65];          // odd stride: conflict-free
    const int tid = threadIdx.x;
    for (int i = tid * 4; i < 4096; i += 1024)
        *(float4*)&Ws[i] = *(const float4*)&W[i];
    const int base = blockIdx.x * 128;
    for (int i = tid; i < 2048; i += 256) {    // 128 rows x 16 float4s
        int r = i >> 4;
        int k = (i & 15) * 4;
        int row = base + r;
        float4 xv = (row < n) ? *(const float4*)&x[(size_t)row * 64 + k]
                              : make_float4(0.f, 0.f, 0.f, 0.f);
        xs[r][k] = xv.x; xs[r][k + 1] = xv.y; xs[r][k + 2] = xv.z; xs[r][k + 3] = xv.w;
    }
    __syncthreads();
    const int cg = tid & 7;    // cols cg*8..+8
    const int rg = tid >> 3;   // rows rg*4..+4
    float acc[4][8] = {};
#pragma unroll 4
    for (int k = 0; k < 64; ++k) {
        float w8[8];
        *(float4*)&w8[0] = *(const float4*)&Ws[k * 64 + cg * 8];
        *(float4*)&w8[4] = *(const float4*)&Ws[k * 64 + cg * 8 + 4];
        float x4[4];
#pragma unroll
        for (int rr = 0; rr < 4; ++rr) x4[rr] = xs[rg * 4 + rr][k];
#pragma unroll
        for (int rr = 0; rr < 4; ++rr)
#pragma unroll
            for (int cc = 0; cc < 8; ++cc)
                acc[rr][cc] = fmaf(x4[rr], w8[cc], acc[rr][cc]);
    }
#pragma unroll
    for (int rr = 0; rr < 4; ++rr) {
        int row = base + rg * 4 + rr;
        if (row >= n) break;
        float d = dis[row];
        float v0 = acc[rr][0] * d, v1 = acc[rr][1] * d;
        float v2 = acc[rr][2] * d, v3 = acc[rr][3] * d;
        float v4 = acc[rr][4] * d, v5 = acc[rr][5] * d;
        float v6 = acc[rr][6] * d, v7 = acc[rr][7] * d;
        int q0 = __builtin_amdgcn_cvt_pk_fp8_f32(v0, v1, 0, false);
        q0 = __builtin_amdgcn_cvt_pk_fp8_f32(v2, v3, q0, true);
        int q1 = __builtin_amdgcn_cvt_pk_fp8_f32(v4, v5, 0, false);
        q1 = __builtin_amdgcn_cvt_pk_fp8_f32(v6, v7, q1, true);
        uint2 q = {(unsigned)q0, (unsigned)q1};
        *(uint2*)&hs8[(size_t)row * 64 + cg * 8] = q;
    }
}

// FUSED layer-1 gather(fp8) + BN1 + ReLU + (act @ W2)*dis -> hs2 (fp8).
// QUARTER-WAVE per node: lane c in [0,16) gathers features 4c..4c+3.
// Matvec: lane computes cols 2c,2c+1; packs both to fp8 in one ushort store.
__global__ __launch_bounds__(256) void k_gather64f8_gemm32(
    const unsigned char* __restrict__ hs8, const int* __restrict__ rowStart,
    const int* __restrict__ perm, const float* __restrict__ dis,
    const float* __restrict__ b, const float* __restrict__ g,
    const float* __restrict__ be, const float* __restrict__ m,
    const float* __restrict__ v, const float* __restrict__ W2,
    unsigned char* __restrict__ hs2f8, int n) {
    __shared__ float W2s[64 * 32];
    __shared__ float actS[16][68];                     // stride 68: conflict-free
    for (int i = threadIdx.x * 4; i < 2048; i += 1024)
        *(float4*)&W2s[i] = *(const float4*)&W2[i];
    __syncthreads();

    const unsigned* hsu = (const unsigned*)hs8;        // [n][16] words of 4 fp8
    int c = threadIdx.x & 15;
    int ln = threadIdx.x >> 4;                         // local node 0..15
    int node = (blockIdx.x * 256 + threadIdx.x) >> 4;
    if (node >= n) return;                             // uniform per quarter-wave
    int r0 = rowStart[node], r1 = rowStart[node + 1];
    float d = dis[node];
    float a0, a1, a2, a3;
    {
        unsigned su = hsu[(size_t)node * 16 + c];      // self term
        floatx2 lo = __builtin_amdgcn_cvt_pk_f32_fp8(su, false);
        floatx2 hi = __builtin_amdgcn_cvt_pk_f32_fp8(su, true);
        a0 = lo[0]; a1 = lo[1]; a2 = hi[0]; a3 = hi[1];
    }
    int e = r0;
    for (; e + 7 < r1; e += 8) {
        int s0 = perm[e],     s1 = perm[e + 1], s2 = perm[e + 2], s3 = perm[e + 3];
        int s4 = perm[e + 4], s5 = perm[e + 5], s6 = perm[e + 6], s7 = perm[e + 7];
        unsigned u0 = hsu[(size_t)s0 * 16 + c];
        unsigned u1 = hsu[(size_t)s1 * 16 + c];
        unsigned u2 = hsu[(size_t)s2 * 16 + c];
        unsigned u3 = hsu[(size_t)s3 * 16 + c];
        unsigned u4 = hsu[(size_t)s4 * 16 + c];
        unsigned u5 = hsu[(size_t)s5 * 16 + c];
        unsigned u6 = hsu[(size_t)s6 * 16 + c];
        unsigned u7 = hsu[(size_t)s7 * 16 + c];
#pragma unroll
        for (int j = 0; j < 8; ++j) {
            unsigned u = j == 0 ? u0 : j == 1 ? u1 : j == 2 ? u2 : j == 3 ? u3
                       : j == 4 ? u4 : j == 5 ? u5 : j == 6 ? u6 : u7;
            floatx2 lo = __builtin_amdgcn_cvt_pk_f32_fp8(u, false);
            floatx2 hi = __builtin_amdgcn_cvt_pk_f32_fp8(u, true);
            a0 += lo[0]; a1 += lo[1]; a2 += hi[0]; a3 += hi[1];
        }
    }
    for (; e < r1; ++e) {
        unsigned u = hsu[(size_t)perm[e] * 16 + c];
        floatx2 lo = __builtin_amdgcn_cvt_pk_f32_fp8(u, false);
        floatx2 hi = __builtin_amdgcn_cvt_pk_f32_fp8(u, true);
        a0 += lo[0]; a1 += lo[1]; a2 += hi[0]; a3 += hi[1];
    }
    int f = 4 * c;
    float4 gv = *(const float4*)&g[f];
    float4 vv = *(const float4*)&v[f];
    float4 bv = *(const float4*)&b[f];
    float4 mv = *(const float4*)&m[f];
    float4 bev = *(const float4*)&be[f];
    float sc0 = gv.x * rsqrtf(vv.x + 1e-5f), sc1 = gv.y * rsqrtf(vv.y + 1e-5f);
    float sc2 = gv.z * rsqrtf(vv.z + 1e-5f), sc3 = gv.w * rsqrtf(vv.w + 1e-5f);
    float y0 = fmaf(a0 * d, sc0, (bv.x - mv.x) * sc0 + bev.x);
    float y1 = fmaf(a1 * d, sc1, (bv.y - mv.y) * sc1 + bev.y);
    float y2 = fmaf(a2 * d, sc2, (bv.z - mv.z) * sc2 + bev.z);
    float y3 = fmaf(a3 * d, sc3, (bv.w - mv.w) * sc3 + bev.w);
    float4 yv = {y0 > 0.f ? y0 : 0.f, y1 > 0.f ? y1 : 0.f,
                 y2 > 0.f ? y2 : 0.f, y3 > 0.f ? y3 : 0.f};
    *(float4*)&actS[ln][f] = yv;   // same-wave producer/consumer (lockstep)

    // cols 2c, 2c+1 of the 64x32 matvec (even/odd banks, broadcast per c)
    float o0 = 0.f, o1 = 0.f;
#pragma unroll
    for (int k = 0; k < 64; ++k) {
        float a = actS[ln][k];
        o0 = fmaf(a, W2s[k * 32 + 2 * c], o0);
        o1 = fmaf(a, W2s[k * 32 + 2 * c + 1], o1);
    }
    int q = __builtin_amdgcn_cvt_pk_fp8_f32(o0 * d, o1 * d, 0, false);
    *(unsigned short*)&hs2f8[(size_t)node * 32 + 2 * c] = (unsigned short)q;
}

// layer-2 gather (fp8 rows, 32B): EIGHTH-WAVE per node, lane c in [0,8)
// handles features 4c..4c+3. One wave-instr = 8 edges.
__global__ __launch_bounds__(256) void k_gather32f8(
    const unsigned char* __restrict__ hs8, const int* __restrict__ rowStart,
    const int* __restrict__ perm, const float* __restrict__ dis,
    const float* __restrict__ b, const float* __restrict__ g,
    const float* __restrict__ be, const float* __restrict__ m,
    const float* __restrict__ v, float* __restrict__ act, int n) {
    const unsigned* hsu = (const unsigned*)hs8;        // [n][8] words of 4 fp8
    int c = threadIdx.x & 7;
    int node = (blockIdx.x * 256 + threadIdx.x) >> 3;
    if (node >= n) return;
    int r0 = rowStart[node], r1 = rowStart[node + 1];
    float d = dis[node];
    float a0, a1, a2, a3;
    {
        unsigned su = hsu[(size_t)node * 8 + c];
        floatx2 lo = __builtin_amdgcn_cvt_pk_f32_fp8(su, false);
        floatx2 hi = __builtin_amdgcn_cvt_pk_f32_fp8(su, true);
        a0 = lo[0]; a1 = lo[1]; a2 = hi[0]; a3 = hi[1];
    }
    int e = r0;
    for (; e + 7 < r1; e += 8) {
        int s0 = perm[e],     s1 = perm[e + 1], s2 = perm[e + 2], s3 = perm[e + 3];
        int s4 = perm[e + 4], s5 = perm[e + 5], s6 = perm[e + 6], s7 = perm[e + 7];
        unsigned u0 = hsu[(size_t)s0 * 8 + c];
        unsigned u1 = hsu[(size_t)s1 * 8 + c];
        unsigned u2 = hsu[(size_t)s2 * 8 + c];
        unsigned u3 = hsu[(size_t)s3 * 8 + c];
        unsigned u4 = hsu[(size_t)s4 * 8 + c];
        unsigned u5 = hsu[(size_t)s5 * 8 + c];
        unsigned u6 = hsu[(size_t)s6 * 8 + c];
        unsigned u7 = hsu[(size_t)s7 * 8 + c];
#pragma unroll
        for (int j = 0; j < 8; ++j) {
            unsigned u = j == 0 ? u0 : j == 1 ? u1 : j == 2 ? u2 : j == 3 ? u3
                       : j == 4 ? u4 : j == 5 ? u5 : j == 6 ? u6 : u7;
            floatx2 lo = __builtin_amdgcn_cvt_pk_f32_fp8(u, false);
            floatx2 hi = __builtin_amdgcn_cvt_pk_f32_fp8(u, true);
            a0 += lo[0]; a1 += lo[1]; a2 += hi[0]; a3 += hi[1];
        }
    }
    for (; e < r1; ++e) {
        unsigned u = hsu[(size_t)perm[e] * 8 + c];
        floatx2 lo = __builtin_amdgcn_cvt_pk_f32_fp8(u, false);
        floatx2 hi = __builtin_amdgcn_cvt_pk_f32_fp8(u, true);
        a0 += lo[0]; a1 += lo[1]; a2 += hi[0]; a3 += hi[1];
    }
    int f = 4 * c;
    float4 gv = *(const float4*)&g[f];
    float4 vv = *(const float4*)&v[f];
    float4 bv = *(const float4*)&b[f];
    float4 mv = *(const float4*)&m[f];
    float4 bev = *(const float4*)&be[f];
    float sc0 = gv.x * rsqrtf(vv.x + 1e-5f), sc1 = gv.y * rsqrtf(vv.y + 1e-5f);
    float sc2 = gv.z * rsqrtf(vv.z + 1e-5f), sc3 = gv.w * rsqrtf(vv.w + 1e-5f);
    float y0 = fmaf(a0 * d, sc0, (bv.x - mv.x) * sc0 + bev.x);
    float y1 = fmaf(a1 * d, sc1, (bv.y - mv.y) * sc1 + bev.y);
    float y2 = fmaf(a2 * d, sc2, (bv.z - mv.z) * sc2 + bev.z);
    float y3 = fmaf(a3 * d, sc3, (bv.w - mv.w) * sc3 + bev.w);
    float4 o = {y0 > 0.f ? y0 : 0.f, y1 > 0.f ? y1 : 0.f,
                y2 > 0.f ? y2 : 0.f, y3 > 0.f ? y3 : 0.f};
    *(float4*)&act[(size_t)node * 32 + f] = o;
}

// mean-pool: batch sorted -> run-length accumulate, few atomics.
__global__ __launch_bounds__(256) void k_pool(
    const float* __restrict__ act2, const int* __restrict__ batch,
    float* __restrict__ sums, float* __restrict__ cnt, int n) {
    int f = threadIdx.x & 31;
    int chunk = (blockIdx.x * blockDim.x + threadIdx.x) >> 5;
    int nchunks = (gridDim.x * blockDim.x) >> 5;
    int per = (n + nchunks - 1) / nchunks;
    int i0 = chunk * per;
    int i1 = min(n, i0 + per);
    if (i0 >= n) return;
    float acc = 0.f, c = 0.f;
    int cur = batch[i0];
    for (int i = i0; i < i1; ++i) {
        int bg = batch[i];
        if (bg != cur) {
            atomicAdd(&sums[(size_t)cur * 32 + f], acc);
            if (f == 0) atomicAdd(&cnt[cur], c);
            acc = 0.f; c = 0.f; cur = bg;
        }
        acc += act2[(size_t)i * 32 + f];
        c += 1.f;
    }
    atomicAdd(&sums[(size_t)cur * 32 + f], acc);
    if (f == 0) atomicAdd(&cnt[cur], c);
}

__global__ void k_mlp(const float* __restrict__ sums, const float* __restrict__ cnt,
                      const float* __restrict__ Wc1, const float* __restrict__ bc1,
                      const float* __restrict__ Wc2, const float* __restrict__ bc2,
                      float* __restrict__ out, int G) {
    int g = blockIdx.x * blockDim.x + threadIdx.x;
    if (g >= G) return;
    float c = cnt[g];
    c = c < 1.f ? 1.f : c;
    float inv = 1.f / c;
    float z[32];
#pragma unroll
    for (int j = 0; j < 32; ++j) z[j] = sums[(size_t)g * 32 + j] * inv;
    float o0 = bc2[0], o1 = bc2[1];
#pragma unroll
    for (int k = 0; k < 16; ++k) {
        float t = bc1[k];
#pragma unroll
        for (int j = 0; j < 32; ++j) t = fmaf(z[j], Wc1[j * 16 + k], t);
        t = t > 0.f ? t : 0.f;
        o0 = fmaf(t, Wc2[k * 2 + 0], o0);
        o1 = fmaf(t, Wc2[k * 2 + 1], o1);
    }
    out[g * 2 + 0] = o0;
    out[g * 2 + 1] = o1;
}

extern "C" void kernel_launch(void* const* d_in, const int* in_sizes, int n_in,
                              void* d_out, int out_size, void* d_ws, size_t ws_size,
                              hipStream_t stream) {
    const float* x   = (const float*)d_in[0];
    const int* ei    = (const int*)d_in[1];
    const int* batch = (const int*)d_in[2];
    const float* W1  = (const float*)d_in[3];
    const float* b1  = (const float*)d_in[4];
    const float* g1  = (const float*)d_in[5];
    const float* be1 = (const float*)d_in[6];
    const float* m1  = (const float*)d_in[7];
    const float* v1  = (const float*)d_in[8];
    const float* W2  = (const float*)d_in[9];
    const float* b2  = (const float*)d_in[10];
    const float* g2  = (const float*)d_in[11];
    const float* be2 = (const float*)d_in[12];
    const float* m2  = (const float*)d_in[13];
    const float* v2  = (const float*)d_in[14];
    const float* Wc1 = (const float*)d_in[15];
    const float* bc1 = (const float*)d_in[16];
    const float* Wc2 = (const float*)d_in[17];
    const float* bc2 = (const float*)d_in[18];

    const int n = in_sizes[2];          // 100000 nodes
    const int E = in_sizes[1] / 2;      // 1000000 edges
    const int G = out_size / 2;         // 500 graphs
    const int* srcI = ei;
    const int* dstI = ei + E;
    const int NB = (n + 255) >> 8;      // buckets of 256 nodes

    // ---- workspace layout (256 B aligned segments) ----
    char* p = (char*)d_ws;
    auto alloc = [&](size_t bytes) {
        char* r = p;
        p += (bytes + 255) & ~(size_t)255;
        return r;
    };
    float*    dis          = (float*)alloc((size_t)n * 4);
    int*      bucketCnt    = (int*)alloc(512 * 4);
    int*      bucketStart  = (int*)alloc(513 * 4);
    int*      bucketCursor = (int*)alloc(512 * 4);
    unsigned* pairs        = (unsigned*)alloc((size_t)E * 4);
    int*      perm         = (int*)alloc((size_t)E * 4);
    int*      rowStart     = (int*)alloc(((size_t)n + 1) * 4);
    unsigned char* hs1f8   = (unsigned char*)alloc((size_t)64 * n);
    unsigned char* hs2f8   = (unsigned char*)alloc((size_t)32 * n);
    float*    act2         = (float*)alloc((size_t)32 * n * 4);
    float*    sums         = (float*)alloc((size_t)32 * G * 4 + (size_t)G * 4);
    float*    cntG         = sums + (size_t)32 * G;

    const int NT = 256;
    const int nbE = (E + CHUNK - 1) / CHUNK;
    const int nSums = G * 33;           // sums + cntG contiguous

    // CSR build (bucketed counting sort), reused by both layers
    k_zero_misc<<<(512 + nSums + NT - 1) / NT, NT, 0, stream>>>(bucketCnt, sums, nSums);
    k_hist<<<nbE, NT, 0, stream>>>(dstI, bucketCnt, E);
    k_scan512<<<1, 512, 0, stream>>>(bucketCnt, bucketStart, bucketCursor);
    k_binpairs<<<nbE, NT, 0, stream>>>(srcI, dstI, bucketCursor, pairs, E);
    k_csr<<<NB, NT, 0, stream>>>(pairs, bucketStart, rowStart, dis, perm, n, E);

    // layer 1 (fp8 hs) + fused layer-2 GEMM (fp8 out)
    k_gemm64<<<(n + 127) / 128, NT, 0, stream>>>(x, W1, dis, hs1f8, n);
    k_gather64f8_gemm32<<<(n * 16 + NT - 1) / NT, NT, 0, stream>>>(
        hs1f8, rowStart, perm, dis, b1, g1, be1, m1, v1, W2, hs2f8, n);

    // layer 2 gather (fp8 rows, L2-resident)
    k_gather32f8<<<(n * 8 + NT - 1) / NT, NT, 0, stream>>>(hs2f8, rowStart, perm, dis,
                                                           b2, g2, be2, m2, v2, act2, n);
    // pool
    k_pool<<<1024, NT, 0, stream>>>(act2, batch, sums, cntG, n);

    // classifier
    k_mlp<<<(G + NT - 1) / NT, NT, 0, stream>>>(sums, cntG, Wc1, bc1, Wc2, bc2,
                                                (float*)d_out, G);
}